// Round 8
// baseline (793.447 us; speedup 1.0000x reference)
//
#include <hip/hip_runtime.h>

#define NN 100000
#define NPAD 100096   // 6256 * 16, padded row count for guard-free GEMM
#define NE 600000
#define EMB 128

typedef unsigned short u16;
typedef unsigned int u32;
typedef unsigned long long u64;
typedef _Float16 half8 __attribute__((ext_vector_type(8)));
typedef float f32x4 __attribute__((ext_vector_type(4)));

__device__ __forceinline__ float4 ld4(const float* p) { return *(const float4*)p; }
__device__ __forceinline__ u32 packh2(float a, float b) {  // two f32 -> packed f16 pair
  union { _Float16 h[2]; u32 d; } u;
  u.h[0] = (_Float16)a;
  u.h[1] = (_Float16)b;
  return u.d;
}

// ---------------- node embedding init: hb(f16) = emb1[x0] + emb2[x1] ----------------
__global__ __launch_bounds__(256) void node_init_kernel(
    const int* __restrict__ x, const float* __restrict__ emb1,
    const float* __restrict__ emb2, _Float16* __restrict__ hb) {
  int tid = blockIdx.x * blockDim.x + threadIdx.x;
  int n = tid >> 4;
  if (n >= NN) return;
  int kc = tid & 15;
  int x0 = min(max(x[2 * n], 0), 118);
  int x1 = min(max(x[2 * n + 1], 0), 2);  // clip to NUM_CHIR-1
  const float* p1 = emb1 + (size_t)x0 * EMB + kc * 8;
  const float* p2 = emb2 + (size_t)x1 * EMB + kc * 8;
  _Float16 o[8];
#pragma unroll
  for (int j = 0; j < 8; ++j) o[j] = (_Float16)(p1[j] + p2[j]);
  *(ulonglong2*)(hb + (size_t)n * EMB + kc * 8) = *(ulonglong2*)o;
}

// ---------------- CSR build ----------------
__global__ __launch_bounds__(256) void hist_kernel(const int* __restrict__ ei,
                                                   int* __restrict__ deg) {
  int e = blockIdx.x * blockDim.x + threadIdx.x;
  if (e >= NE) return;
  atomicAdd(&deg[ei[NE + e]], 1);
}

// scan1 + degree-histogram (fused dhist)
__global__ __launch_bounds__(256) void scan1_kernel(const int* __restrict__ deg,
                                                    int* __restrict__ off,
                                                    int* __restrict__ bsum,
                                                    int* __restrict__ gbins) {
  __shared__ int s[256];
  __shared__ int l[33];
  int t = threadIdx.x;
  if (t < 33) l[t] = 0;
  int base = blockIdx.x * 1024 + t * 4;
  int v[4];
#pragma unroll
  for (int j = 0; j < 4; ++j) {
    int idx = base + j;
    v[j] = (idx < NN) ? deg[idx] : 0;
  }
  int tsum = v[0] + v[1] + v[2] + v[3];
  s[t] = tsum;
  __syncthreads();
  for (int d = 1; d < 256; d <<= 1) {
    int add = (t >= d) ? s[t - d] : 0;
    __syncthreads();
    s[t] += add;
    __syncthreads();
  }
  int run = s[t] - tsum;
#pragma unroll
  for (int j = 0; j < 4; ++j) {
    int idx = base + j;
    if (idx < NN) {
      off[idx] = run;
      atomicAdd(&l[32 - min(v[j], 32)], 1);
    }
    run += v[j];
  }
  if (t == 255) bsum[blockIdx.x] = s[255];
  __syncthreads();
  if (t < 33 && l[t]) atomicAdd(&gbins[t], l[t]);
}

// wave0: prefix-scan of block sums; wave1: prefix-scan of degree bins (fused dscan)
__global__ void scan2_kernel(int* __restrict__ bsum, int* __restrict__ off, int nb,
                             int* __restrict__ gbins) {
  int t = threadIdx.x;  // 128 threads
  if (t < 64) {
    int lane = t;
    int v0 = (lane < nb) ? bsum[lane] : 0;
    int v1 = (lane + 64 < nb) ? bsum[lane + 64] : 0;
    int s0 = v0, s1 = v1;
    for (int d = 1; d < 64; d <<= 1) {
      int t0 = __shfl_up(s0, d);
      int t1 = __shfl_up(s1, d);
      if (lane >= d) { s0 += t0; s1 += t1; }
    }
    int tot0 = __shfl(s0, 63);
    int tot1 = __shfl(s1, 63);
    if (lane < nb) bsum[lane] = s0 - v0;                 // exclusive prefix
    if (lane + 64 < nb) bsum[lane + 64] = tot0 + s1 - v1;
    if (lane == 0) off[NN] = tot0 + tot1;
  } else {
    int lane = t - 64;
    int v = (lane < 33) ? gbins[lane] : 0;
    int s = v;
    for (int d = 1; d < 64; d <<= 1) {
      int tt = __shfl_up(s, d);
      if (lane >= d) s += tt;
    }
    if (lane < 33) gbins[lane] = s - v;  // exclusive bin starts
  }
}

// scan3 + degree-bucket scatter (fused dscatter): perm = nodes in DESCENDING degree
__global__ __launch_bounds__(256) void scan3_kernel(int* __restrict__ off,
                                                    const int* __restrict__ bsum,
                                                    const int* __restrict__ deg,
                                                    int* __restrict__ gbins,
                                                    int* __restrict__ perm) {
  __shared__ int lcnt[33], lbase[33];
  int t = threadIdx.x;
  if (t < 33) lcnt[t] = 0;
  __syncthreads();
  int idx = blockIdx.x * 256 + t;
  int b = 0, r = 0;
  if (idx < NN) {
    off[idx] += bsum[idx >> 10];
    b = 32 - min(deg[idx], 32);
    r = atomicAdd(&lcnt[b], 1);
  }
  __syncthreads();
  if (t < 33) lbase[t] = lcnt[t] ? atomicAdd(&gbins[t], lcnt[t]) : 0;
  __syncthreads();
  if (idx < NN) perm[lbase[b] + r] = idx;
}

__global__ __launch_bounds__(256) void scatter_kernel(
    const int* __restrict__ ei, const int* __restrict__ ea,
    const int* __restrict__ off, int* __restrict__ cnt, int* __restrict__ csr) {
  int e = blockIdx.x * blockDim.x + threadIdx.x;
  if (e >= NE) return;
  int d = ei[NE + e];
  int s = ei[e];
  int a0 = min(max(ea[2 * e], 0), 4);
  int a1 = min(max(ea[2 * e + 1], 0), 2);
  int code = a0 * 3 + a1;  // [0,14]
  int r = atomicAdd(&cnt[d], 1);
  csr[off[d] + r] = s | (code << 20);
}

// ---------------- merged weight/combo prep: frag-ordered f16 W1/W2 + f16 combos ------
__global__ __launch_bounds__(256) void prep_kernel(
    const float* __restrict__ W1g, const float* __restrict__ W2g,
    const float* __restrict__ ee1, const float* __restrict__ ee2,
    _Float16* __restrict__ W1f, _Float16* __restrict__ W2f,
    _Float16* __restrict__ cbh) {
  int idx = blockIdx.x * blockDim.x + threadIdx.x;
  _Float16 o[8];
  if (idx < 20480) {
    int lane = idx & 63;
    int r = idx >> 6;             // l*64 + c*16 + kt*4 + colt
    int nt = r & 3, kt = (r >> 2) & 3, c = (r >> 4) & 3, l = r >> 6;
    int n = c * 64 + nt * 16 + (lane & 15);
    int kb = kt * 32 + (lane >> 4) * 8;
#pragma unroll
    for (int j = 0; j < 8; ++j) o[j] = (_Float16)W1g[((size_t)l * 128 + kb + j) * 256 + n];
    *(ulonglong2*)(W1f + (size_t)idx * 8) = *(ulonglong2*)o;
  } else if (idx < 40960) {
    int i2 = idx - 20480;
    int lane = i2 & 63;
    int r = i2 >> 6;              // l*64 + c*16 + ktl*8 + nt
    int nt = r & 7, ktl = (r >> 3) & 1, c = (r >> 4) & 3, l = r >> 6;
    int n = nt * 16 + (lane & 15);
    int kb = c * 64 + ktl * 32 + (lane >> 4) * 8;
#pragma unroll
    for (int j = 0; j < 8; ++j) o[j] = (_Float16)W2g[((size_t)l * 256 + kb + j) * 128 + n];
    *(ulonglong2*)(W2f + (size_t)i2 * 8) = *(ulonglong2*)o;
  } else if (idx < 40960 + 9600) {
    int i3 = idx - 40960;
    int l = i3 / (15 * 128);
    int rem = i3 % (15 * 128);
    int code = rem / 128;
    int f = rem % 128;
    cbh[i3] = (_Float16)(ee1[(l * 5 + code / 3) * 128 + f] + ee2[(l * 3 + code % 3) * 128 + f]);
  }
}

// ---------------- agg (+fused BN stats): Af = (1+eps)*h' + relu(h'+c0) + sum relu(...) --
// NORM: h' = relu(hsrc*sc + sh) with sc/sh computed IN-BLOCK from the previous layer's
// BN partial slots (replaces the separate stats_kernel dispatch; identical reduction
// order -> bitwise-identical scale/shift).
template <bool NORM>
__global__ __launch_bounds__(256) void agg_kernel(
    const _Float16* __restrict__ hsrc, const float* __restrict__ slots,
    const float* __restrict__ gamma, const float* __restrict__ beta,
    const int* __restrict__ off, const int* __restrict__ csr,
    const _Float16* __restrict__ cbh, const float* __restrict__ epsp,
    const int* __restrict__ perm, _Float16* __restrict__ Af) {
  __shared__ float s_sc[128], s_sh[128];
  int t = threadIdx.x;
  if (NORM) {
    if (t < 128) {
      float s = 0.f, s2 = 0.f;
#pragma unroll 8
      for (int k = 0; k < 32; ++k) {
        s += slots[k * 256 + t];
        s2 += slots[k * 256 + 128 + t];
      }
      float mean = s * (1.0f / NN);
      float var = s2 * (1.0f / NN) - mean * mean;  // biased
      float sc = gamma[t] * rsqrtf(var + 1e-5f);
      s_sc[t] = sc;
      s_sh[t] = beta[t] - mean * sc;
    }
    __syncthreads();
  }
  int tid = blockIdx.x * blockDim.x + t;
  int g = tid >> 4;
  int kc = tid & 15;
  float av[8] = {0.f, 0.f, 0.f, 0.f, 0.f, 0.f, 0.f, 0.f};
  float scv[8], shv[8];
  if (NORM) {
#pragma unroll
    for (int j = 0; j < 8; ++j) {
      scv[j] = s_sc[kc * 8 + j];
      shv[j] = s_sh[kc * 8 + j];
    }
  }
  int node = g;  // pad rows keep identity (write zeros)
  if (g < NN) {
    node = perm[g];
    const float eps1 = 1.0f + *epsp;
    ulonglong2 hraw = *(const ulonglong2*)(hsrc + (size_t)node * EMB + kc * 8);
    _Float16* hr = (_Float16*)&hraw;
    half8 c0 = *(const half8*)(cbh + kc * 8);  // self-loop combo (code 0)
#pragma unroll
    for (int j = 0; j < 8; ++j) {
      float hv = (float)hr[j];
      if (NORM) hv = fmaxf(hv * scv[j] + shv[j], 0.f);
      av[j] = eps1 * hv + fmaxf(hv + (float)c0[j], 0.f);
    }
    int s0 = off[node], s1 = off[node + 1];
    int e = s0;
    for (; e + 3 < s1; e += 4) {  // unroll x4: four gather chains in flight
      int p0 = csr[e], p1 = csr[e + 1], p2 = csr[e + 2], p3 = csr[e + 3];
      ulonglong2 r0 = *(const ulonglong2*)(hsrc + (size_t)(p0 & 0xFFFFF) * EMB + kc * 8);
      ulonglong2 r1 = *(const ulonglong2*)(hsrc + (size_t)(p1 & 0xFFFFF) * EMB + kc * 8);
      ulonglong2 r2 = *(const ulonglong2*)(hsrc + (size_t)(p2 & 0xFFFFF) * EMB + kc * 8);
      ulonglong2 r3 = *(const ulonglong2*)(hsrc + (size_t)(p3 & 0xFFFFF) * EMB + kc * 8);
      ulonglong2 rr[4] = {r0, r1, r2, r3};
      int pp[4] = {p0, p1, p2, p3};
#pragma unroll
      for (int u = 0; u < 4; ++u) {
        half8 cc = *(const half8*)(cbh + (size_t)(pp[u] >> 20) * EMB + kc * 8);
        _Float16* sp = (_Float16*)&rr[u];
#pragma unroll
        for (int j = 0; j < 8; ++j) {
          float v = (float)sp[j];
          if (NORM) v = fmaxf(v * scv[j] + shv[j], 0.f);
          av[j] += fmaxf(v + (float)cc[j], 0.f);
        }
      }
    }
    for (; e < s1; ++e) {
      int p0 = csr[e];
      ulonglong2 r0 = *(const ulonglong2*)(hsrc + (size_t)(p0 & 0xFFFFF) * EMB + kc * 8);
      half8 cc = *(const half8*)(cbh + (size_t)(p0 >> 20) * EMB + kc * 8);
      _Float16* sp = (_Float16*)&r0;
#pragma unroll
      for (int j = 0; j < 8; ++j) {
        float v = (float)sp[j];
        if (NORM) v = fmaxf(v * scv[j] + shv[j], 0.f);
        av[j] += fmaxf(v + (float)cc[j], 0.f);
      }
    }
  }
  _Float16 o[8];
#pragma unroll
  for (int j = 0; j < 8; ++j) o[j] = (_Float16)av[j];
  *(ulonglong2*)(Af + (size_t)node * EMB + kc * 8) = *(ulonglong2*)o;
}

// ---------------- mlp v4: NO LDS, NO barriers — W fragments direct from L2 ----------
// Same 16-node-per-wave tiling and shfl transpose as R0 (proven numerics); the W-chunk
// (16KB/layer-chunk) is identical across all waves -> L2-broadcast. Waves are fully
// independent: no lock-step barrier drains, latency hidden by resident waves.
__global__ __launch_bounds__(256, 4) void mlp_kernel(
    const _Float16* __restrict__ Af, const _Float16* __restrict__ W1f,
    const _Float16* __restrict__ W2f,
    const float* __restrict__ b1g, const float* __restrict__ b2g,
    _Float16* __restrict__ hpre, float* __restrict__ slots) {
  const int t = threadIdx.x;
  const int w = t >> 6;
  const int lane = t & 63;
  const int q = lane >> 4, l15 = lane & 15;
  const int gw = blockIdx.x * 4 + w;   // global wave id, 0..6255
  const int n0 = gw * 16;              // 16 nodes per wave
  float* sums = slots + (size_t)(gw & 31) * 256;

  const half8* W1v = (const half8*)W1f;  // frag r at W1v[r*64 + lane]
  const half8* W2v = (const half8*)W2f;

  // ---- A fragments loaded ONCE, held across all chunks ----
  half8 nh[4];
#pragma unroll
  for (int kt = 0; kt < 4; ++kt)
    nh[kt] = *(const half8*)(Af + (size_t)(n0 + l15) * EMB + kt * 32 + q * 8);

  f32x4 oacc[8];  // [out col tile]
#pragma unroll
  for (int a = 0; a < 8; ++a) oacc[a] = (f32x4){0.f, 0.f, 0.f, 0.f};

  const int srcA = ((q & 1) * 2) * 16 + l15;  // quad permutation sources
  const int srcB = srcA + 16;
  const bool sel = (q >> 1) != 0;

#pragma unroll
  for (int c = 0; c < 4; ++c) {
    // ---- stage 1: hmidT[col c*64+colt*16+q*4+r][node l15] ----
    f32x4 hacc[4];
#pragma unroll
    for (int a = 0; a < 4; ++a) hacc[a] = (f32x4){0.f, 0.f, 0.f, 0.f};
#pragma unroll
    for (int kt = 0; kt < 4; ++kt) {
#pragma unroll
      for (int colt = 0; colt < 4; ++colt) {
        half8 wh = W1v[(size_t)(c * 16 + kt * 4 + colt) * 64 + lane];
        hacc[colt] = __builtin_amdgcn_mfma_f32_16x16x32_f16(wh, nh[kt], hacc[colt], 0, 0, 0);
      }
    }

    // ---- bias + relu + pack to f16 pairs ----
    u32 P01[4], P23[4];  // [colt]
#pragma unroll
    for (int colt = 0; colt < 4; ++colt) {
      float4 b1v = ld4(b1g + c * 64 + colt * 16 + q * 4);
      float v0 = fmaxf(hacc[colt][0] + b1v.x, 0.f);
      float v1 = fmaxf(hacc[colt][1] + b1v.y, 0.f);
      float v2 = fmaxf(hacc[colt][2] + b1v.z, 0.f);
      float v3 = fmaxf(hacc[colt][3] + b1v.w, 0.f);
      P01[colt] = packh2(v0, v1);
      P23[colt] = packh2(v2, v3);
    }

    // ---- stage 2: quad-permute hmid into B-frags, multiply with W2 from L2 ----
#pragma unroll
    for (int ktl = 0; ktl < 2; ++ktl) {
      half8 bh;
      {
        union { u32 d[4]; half8 s; } uh;
        int c0 = 2 * ktl, c1 = 2 * ktl + 1;
        u32 a0, a1;
        a0 = (u32)__shfl((int)P01[c0], srcA); a1 = (u32)__shfl((int)P01[c1], srcA);
        uh.d[0] = sel ? a1 : a0;
        a0 = (u32)__shfl((int)P23[c0], srcA); a1 = (u32)__shfl((int)P23[c1], srcA);
        uh.d[1] = sel ? a1 : a0;
        a0 = (u32)__shfl((int)P01[c0], srcB); a1 = (u32)__shfl((int)P01[c1], srcB);
        uh.d[2] = sel ? a1 : a0;
        a0 = (u32)__shfl((int)P23[c0], srcB); a1 = (u32)__shfl((int)P23[c1], srcB);
        uh.d[3] = sel ? a1 : a0;
        bh = uh.s;
      }
#pragma unroll
      for (int nt = 0; nt < 8; ++nt) {
        half8 wh = W2v[(size_t)(c * 16 + ktl * 8 + nt) * 64 + lane];
        oacc[nt] = __builtin_amdgcn_mfma_f32_16x16x32_f16(wh, bh, oacc[nt], 0, 0, 0);
      }
    }
  }

  // ---- epilogue: +b2, packed f16 store (8B), BN partials into slot ----
  const int node = n0 + l15;
#pragma unroll
  for (int nt = 0; nt < 8; ++nt) {
    int ocb = nt * 16 + q * 4;  // 4 consecutive out cols per lane
    float4 b2v = ld4(b2g + ocb);
    f32x4 s = (f32x4){0.f, 0.f, 0.f, 0.f};
    f32x4 s2 = (f32x4){0.f, 0.f, 0.f, 0.f};
    if (node < NN) {
      float v0 = oacc[nt][0] + b2v.x;
      float v1 = oacc[nt][1] + b2v.y;
      float v2 = oacc[nt][2] + b2v.z;
      float v3 = oacc[nt][3] + b2v.w;
      u64 pk = (u64)packh2(v0, v1) | ((u64)packh2(v2, v3) << 32);
      *(u64*)(hpre + (size_t)node * EMB + ocb) = pk;
      s[0] = v0; s[1] = v1; s[2] = v2; s[3] = v3;
      s2[0] = v0 * v0; s2[1] = v1 * v1; s2[2] = v2 * v2; s2[3] = v3 * v3;
    }
#pragma unroll
    for (int d = 1; d < 16; d <<= 1) {
#pragma unroll
      for (int r = 0; r < 4; ++r) {
        s[r] += __shfl_xor(s[r], d);
        s2[r] += __shfl_xor(s2[r], d);
      }
    }
    if (l15 == 0) {
#pragma unroll
      for (int r = 0; r < 4; ++r) {
        atomicAdd(&sums[ocb + r], s[r]);
        atomicAdd(&sums[128 + ocb + r], s2[r]);
      }
    }
  }
}

// ---------------- final output: out = hpre*sc + sh (f32, no relu); stats in-block ----
__global__ __launch_bounds__(256) void out_kernel(
    const _Float16* __restrict__ hpre, const float* __restrict__ slots,
    const float* __restrict__ gamma, const float* __restrict__ beta,
    float* __restrict__ out) {
  __shared__ float s_sc[128], s_sh[128];
  int t = threadIdx.x;
  if (t < 128) {
    float s = 0.f, s2 = 0.f;
#pragma unroll 8
    for (int k = 0; k < 32; ++k) {
      s += slots[k * 256 + t];
      s2 += slots[k * 256 + 128 + t];
    }
    float mean = s * (1.0f / NN);
    float var = s2 * (1.0f / NN) - mean * mean;  // biased
    float sc = gamma[t] * rsqrtf(var + 1e-5f);
    s_sc[t] = sc;
    s_sh[t] = beta[t] - mean * sc;
  }
  __syncthreads();
  int tid = blockIdx.x * blockDim.x + t;
  int n = tid >> 4;
  if (n >= NN) return;
  int kc = tid & 15;
  ulonglong2 raw = *(const ulonglong2*)(hpre + (size_t)n * EMB + kc * 8);
  _Float16* hr = (_Float16*)&raw;
  float v[8];
#pragma unroll
  for (int j = 0; j < 8; ++j) v[j] = (float)hr[j] * s_sc[kc * 8 + j] + s_sh[kc * 8 + j];
  float* d = out + (size_t)n * EMB + kc * 8;
  *(float4*)d = make_float4(v[0], v[1], v[2], v[3]);
  *(float4*)(d + 4) = make_float4(v[4], v[5], v[6], v[7]);
}

// ---------------- launch ----------------
extern "C" void kernel_launch(void* const* d_in, const int* in_sizes, int n_in,
                              void* d_out, int out_size, void* d_ws, size_t ws_size,
                              hipStream_t stream) {
  const int* x = (const int*)d_in[0];
  const int* ei = (const int*)d_in[1];
  const int* ea = (const int*)d_in[2];
  const float* x_emb1 = (const float*)d_in[3];
  const float* x_emb2 = (const float*)d_in[4];
  const float* ee1 = (const float*)d_in[5];
  const float* ee2 = (const float*)d_in[6];
  const float* W1 = (const float*)d_in[7];
  const float* b1 = (const float*)d_in[8];
  const float* W2 = (const float*)d_in[9];
  const float* b2 = (const float*)d_in[10];
  const float* eps = (const float*)d_in[11];
  const float* gamma = (const float*)d_in[12];
  const float* beta = (const float*)d_in[13];
  float* out = (float*)d_out;

  // workspace layout (16B-aligned sections)
  float* slots = (float*)d_ws;                  // 5*32*256 BN partial slots
  _Float16* hpre = (_Float16*)(slots + 5 * 32 * 256);  // NN*128 f16
  _Float16* Af = hpre + (size_t)NN * EMB;       // NPAD*128 f16
  _Float16* hb = Af + (size_t)NPAD * EMB;       // NN*128 f16
  _Float16* W1f = hb + (size_t)NN * EMB;        // 5*32768 f16
  _Float16* W2f = W1f + 5 * 32768;              // 5*32768 f16
  _Float16* cbh = W2f + 5 * 32768;              // 5*15*128 f16 combos
  int* deg = (int*)(cbh + 5 * 15 * 128 + 64);   // NN (pad to 16B boundary)
  int* off = deg + NN;                          // NN+1
  int* csr = off + NN + 1;                      // NE
  int* bsum = csr + NE;                         // 128
  int* gbins = bsum + 128;                      // 64 degree-bin starts
  int* perm = gbins + 64;                       // NN degree-sorted node order

  const int NB_SCAN = (NN + 1023) / 1024;

  // one-time per launch: CSR + degree-sort + combo tables + frag-ordered f16 weights
  hipMemsetAsync(deg, 0, NN * sizeof(int), stream);
  hipMemsetAsync(gbins, 0, 64 * sizeof(int), stream);
  hipMemsetAsync(slots, 0, 5 * 32 * 256 * sizeof(float), stream);
  hist_kernel<<<(NE + 255) / 256, 256, 0, stream>>>(ei, deg);
  scan1_kernel<<<NB_SCAN, 256, 0, stream>>>(deg, off, bsum, gbins);
  scan2_kernel<<<1, 128, 0, stream>>>(bsum, off, NB_SCAN, gbins);
  scan3_kernel<<<(NN + 255) / 256, 256, 0, stream>>>(off, bsum, deg, gbins, perm);
  hipMemsetAsync(deg, 0, NN * sizeof(int), stream);
  scatter_kernel<<<(NE + 255) / 256, 256, 0, stream>>>(ei, ea, off, deg, csr);
  prep_kernel<<<(40960 + 9600 + 255) / 256, 256, 0, stream>>>(W1, W2, ee1, ee2, W1f,
                                                              W2f, cbh);
  node_init_kernel<<<NN * 16 / 256 + 1, 256, 0, stream>>>(x, x_emb1, x_emb2, hb);

  const int NBLK = NPAD / 64;  // 1564 blocks x 4 waves (16 nodes each)
  for (int i = 0; i < 5; ++i) {
    if (i == 0)
      agg_kernel<false><<<NPAD * 16 / 256, 256, 0, stream>>>(
          hb, nullptr, nullptr, nullptr, off, csr, cbh + (size_t)i * 15 * EMB,
          eps + i, perm, Af);
    else
      agg_kernel<true><<<NPAD * 16 / 256, 256, 0, stream>>>(
          hpre, slots + (size_t)(i - 1) * 32 * 256, gamma + (size_t)(i - 1) * EMB,
          beta + (size_t)(i - 1) * EMB, off, csr, cbh + (size_t)i * 15 * EMB,
          eps + i, perm, Af);
    mlp_kernel<<<NBLK, 256, 0, stream>>>(
        Af, W1f + (size_t)i * 32768, W2f + (size_t)i * 32768,
        b1 + (size_t)i * 256, b2 + (size_t)i * 128, hpre,
        slots + (size_t)i * 32 * 256);
  }
  out_kernel<<<NN * 16 / 256 + 1, 256, 0, stream>>>(
      hpre, slots + 4 * 32 * 256, gamma + 4 * EMB, beta + 4 * EMB, out);
}

// Round 9
// 651.162 us; speedup vs baseline: 1.2185x; 1.2185x over previous
//
#include <hip/hip_runtime.h>

#define NN 100000
#define NPAD 100096   // 6256 * 16, padded row count for guard-free GEMM
#define NE 600000
#define EMB 128

typedef unsigned short u16;
typedef unsigned int u32;
typedef unsigned long long u64;
typedef _Float16 half8 __attribute__((ext_vector_type(8)));
typedef float f32x4 __attribute__((ext_vector_type(4)));

__device__ __forceinline__ float4 ld4(const float* p) { return *(const float4*)p; }
__device__ __forceinline__ u32 packh2(float a, float b) {  // two f32 -> packed f16 pair
  union { _Float16 h[2]; u32 d; } u;
  u.h[0] = (_Float16)a;
  u.h[1] = (_Float16)b;
  return u.d;
}

// ---------------- node embedding init: hb(f16) = emb1[x0] + emb2[x1] ----------------
__global__ __launch_bounds__(256) void node_init_kernel(
    const int* __restrict__ x, const float* __restrict__ emb1,
    const float* __restrict__ emb2, _Float16* __restrict__ hb) {
  int tid = blockIdx.x * blockDim.x + threadIdx.x;
  int n = tid >> 4;
  if (n >= NN) return;
  int kc = tid & 15;
  int x0 = min(max(x[2 * n], 0), 118);
  int x1 = min(max(x[2 * n + 1], 0), 2);  // clip to NUM_CHIR-1
  const float* p1 = emb1 + (size_t)x0 * EMB + kc * 8;
  const float* p2 = emb2 + (size_t)x1 * EMB + kc * 8;
  _Float16 o[8];
#pragma unroll
  for (int j = 0; j < 8; ++j) o[j] = (_Float16)(p1[j] + p2[j]);
  *(ulonglong2*)(hb + (size_t)n * EMB + kc * 8) = *(ulonglong2*)o;
}

// ---------------- CSR build ----------------
__global__ __launch_bounds__(256) void hist_kernel(const int* __restrict__ ei,
                                                   int* __restrict__ deg) {
  int e = blockIdx.x * blockDim.x + threadIdx.x;
  if (e >= NE) return;
  atomicAdd(&deg[ei[NE + e]], 1);
}

// scan1 + degree-histogram (fused dhist)
__global__ __launch_bounds__(256) void scan1_kernel(const int* __restrict__ deg,
                                                    int* __restrict__ off,
                                                    int* __restrict__ bsum,
                                                    int* __restrict__ gbins) {
  __shared__ int s[256];
  __shared__ int l[33];
  int t = threadIdx.x;
  if (t < 33) l[t] = 0;
  int base = blockIdx.x * 1024 + t * 4;
  int v[4];
#pragma unroll
  for (int j = 0; j < 4; ++j) {
    int idx = base + j;
    v[j] = (idx < NN) ? deg[idx] : 0;
  }
  int tsum = v[0] + v[1] + v[2] + v[3];
  s[t] = tsum;
  __syncthreads();
  for (int d = 1; d < 256; d <<= 1) {
    int add = (t >= d) ? s[t - d] : 0;
    __syncthreads();
    s[t] += add;
    __syncthreads();
  }
  int run = s[t] - tsum;
#pragma unroll
  for (int j = 0; j < 4; ++j) {
    int idx = base + j;
    if (idx < NN) {
      off[idx] = run;
      atomicAdd(&l[32 - min(v[j], 32)], 1);
    }
    run += v[j];
  }
  if (t == 255) bsum[blockIdx.x] = s[255];
  __syncthreads();
  if (t < 33 && l[t]) atomicAdd(&gbins[t], l[t]);
}

// wave0: prefix-scan of block sums; wave1: prefix-scan of degree bins (fused dscan)
__global__ void scan2_kernel(int* __restrict__ bsum, int* __restrict__ off, int nb,
                             int* __restrict__ gbins) {
  int t = threadIdx.x;  // 128 threads
  if (t < 64) {
    int lane = t;
    int v0 = (lane < nb) ? bsum[lane] : 0;
    int v1 = (lane + 64 < nb) ? bsum[lane + 64] : 0;
    int s0 = v0, s1 = v1;
    for (int d = 1; d < 64; d <<= 1) {
      int t0 = __shfl_up(s0, d);
      int t1 = __shfl_up(s1, d);
      if (lane >= d) { s0 += t0; s1 += t1; }
    }
    int tot0 = __shfl(s0, 63);
    int tot1 = __shfl(s1, 63);
    if (lane < nb) bsum[lane] = s0 - v0;                 // exclusive prefix
    if (lane + 64 < nb) bsum[lane + 64] = tot0 + s1 - v1;
    if (lane == 0) off[NN] = tot0 + tot1;
  } else {
    int lane = t - 64;
    int v = (lane < 33) ? gbins[lane] : 0;
    int s = v;
    for (int d = 1; d < 64; d <<= 1) {
      int tt = __shfl_up(s, d);
      if (lane >= d) s += tt;
    }
    if (lane < 33) gbins[lane] = s - v;  // exclusive bin starts
  }
}

// scan3 + degree-bucket scatter (fused dscatter): perm = nodes in DESCENDING degree
__global__ __launch_bounds__(256) void scan3_kernel(int* __restrict__ off,
                                                    const int* __restrict__ bsum,
                                                    const int* __restrict__ deg,
                                                    int* __restrict__ gbins,
                                                    int* __restrict__ perm) {
  __shared__ int lcnt[33], lbase[33];
  int t = threadIdx.x;
  if (t < 33) lcnt[t] = 0;
  __syncthreads();
  int idx = blockIdx.x * 256 + t;
  int b = 0, r = 0;
  if (idx < NN) {
    off[idx] += bsum[idx >> 10];
    b = 32 - min(deg[idx], 32);
    r = atomicAdd(&lcnt[b], 1);
  }
  __syncthreads();
  if (t < 33) lbase[t] = lcnt[t] ? atomicAdd(&gbins[t], lcnt[t]) : 0;
  __syncthreads();
  if (idx < NN) perm[lbase[b] + r] = idx;
}

__global__ __launch_bounds__(256) void scatter_kernel(
    const int* __restrict__ ei, const int* __restrict__ ea,
    const int* __restrict__ off, int* __restrict__ cnt, int* __restrict__ csr) {
  int e = blockIdx.x * blockDim.x + threadIdx.x;
  if (e >= NE) return;
  int d = ei[NE + e];
  int s = ei[e];
  int a0 = min(max(ea[2 * e], 0), 4);
  int a1 = min(max(ea[2 * e + 1], 0), 2);
  int code = a0 * 3 + a1;  // [0,14]
  int r = atomicAdd(&cnt[d], 1);
  csr[off[d] + r] = s | (code << 20);
}

// ---------------- merged weight/combo prep: frag-ordered f16 W1/W2 + f16 combos ------
__global__ __launch_bounds__(256) void prep_kernel(
    const float* __restrict__ W1g, const float* __restrict__ W2g,
    const float* __restrict__ ee1, const float* __restrict__ ee2,
    _Float16* __restrict__ W1f, _Float16* __restrict__ W2f,
    _Float16* __restrict__ cbh) {
  int idx = blockIdx.x * blockDim.x + threadIdx.x;
  _Float16 o[8];
  if (idx < 20480) {
    int lane = idx & 63;
    int r = idx >> 6;             // l*64 + c*16 + kt*4 + colt
    int nt = r & 3, kt = (r >> 2) & 3, c = (r >> 4) & 3, l = r >> 6;
    int n = c * 64 + nt * 16 + (lane & 15);
    int kb = kt * 32 + (lane >> 4) * 8;
#pragma unroll
    for (int j = 0; j < 8; ++j) o[j] = (_Float16)W1g[((size_t)l * 128 + kb + j) * 256 + n];
    *(ulonglong2*)(W1f + (size_t)idx * 8) = *(ulonglong2*)o;
  } else if (idx < 40960) {
    int i2 = idx - 20480;
    int lane = i2 & 63;
    int r = i2 >> 6;              // l*64 + c*16 + ktl*8 + nt
    int nt = r & 7, ktl = (r >> 3) & 1, c = (r >> 4) & 3, l = r >> 6;
    int n = nt * 16 + (lane & 15);
    int kb = c * 64 + ktl * 32 + (lane >> 4) * 8;
#pragma unroll
    for (int j = 0; j < 8; ++j) o[j] = (_Float16)W2g[((size_t)l * 256 + kb + j) * 128 + n];
    *(ulonglong2*)(W2f + (size_t)i2 * 8) = *(ulonglong2*)o;
  } else if (idx < 40960 + 9600) {
    int i3 = idx - 40960;
    int l = i3 / (15 * 128);
    int rem = i3 % (15 * 128);
    int code = rem / 128;
    int f = rem % 128;
    cbh[i3] = (_Float16)(ee1[(l * 5 + code / 3) * 128 + f] + ee2[(l * 3 + code % 3) * 128 + f]);
  }
}

// ---------------- agg (+fused BN stats): Af = (1+eps)*h' + relu(h'+c0) + sum relu(...) --
// NORM: h' = relu(hsrc*sc + sh) with sc/sh computed IN-BLOCK from the previous layer's
// BN partial slots (identical reduction order -> bitwise-identical scale/shift).
template <bool NORM>
__global__ __launch_bounds__(256) void agg_kernel(
    const _Float16* __restrict__ hsrc, const float* __restrict__ slots,
    const float* __restrict__ gamma, const float* __restrict__ beta,
    const int* __restrict__ off, const int* __restrict__ csr,
    const _Float16* __restrict__ cbh, const float* __restrict__ epsp,
    const int* __restrict__ perm, _Float16* __restrict__ Af) {
  __shared__ float s_sc[128], s_sh[128];
  int t = threadIdx.x;
  if (NORM) {
    if (t < 128) {
      float s = 0.f, s2 = 0.f;
#pragma unroll 8
      for (int k = 0; k < 32; ++k) {
        s += slots[k * 256 + t];
        s2 += slots[k * 256 + 128 + t];
      }
      float mean = s * (1.0f / NN);
      float var = s2 * (1.0f / NN) - mean * mean;  // biased
      float sc = gamma[t] * rsqrtf(var + 1e-5f);
      s_sc[t] = sc;
      s_sh[t] = beta[t] - mean * sc;
    }
    __syncthreads();
  }
  int tid = blockIdx.x * blockDim.x + t;
  int g = tid >> 4;
  int kc = tid & 15;
  float av[8] = {0.f, 0.f, 0.f, 0.f, 0.f, 0.f, 0.f, 0.f};
  float scv[8], shv[8];
  if (NORM) {
#pragma unroll
    for (int j = 0; j < 8; ++j) {
      scv[j] = s_sc[kc * 8 + j];
      shv[j] = s_sh[kc * 8 + j];
    }
  }
  int node = g;  // pad rows keep identity (write zeros)
  if (g < NN) {
    node = perm[g];
    const float eps1 = 1.0f + *epsp;
    ulonglong2 hraw = *(const ulonglong2*)(hsrc + (size_t)node * EMB + kc * 8);
    _Float16* hr = (_Float16*)&hraw;
    half8 c0 = *(const half8*)(cbh + kc * 8);  // self-loop combo (code 0)
#pragma unroll
    for (int j = 0; j < 8; ++j) {
      float hv = (float)hr[j];
      if (NORM) hv = fmaxf(hv * scv[j] + shv[j], 0.f);
      av[j] = eps1 * hv + fmaxf(hv + (float)c0[j], 0.f);
    }
    int s0 = off[node], s1 = off[node + 1];
    int e = s0;
    for (; e + 3 < s1; e += 4) {  // unroll x4: four gather chains in flight
      int p0 = csr[e], p1 = csr[e + 1], p2 = csr[e + 2], p3 = csr[e + 3];
      ulonglong2 r0 = *(const ulonglong2*)(hsrc + (size_t)(p0 & 0xFFFFF) * EMB + kc * 8);
      ulonglong2 r1 = *(const ulonglong2*)(hsrc + (size_t)(p1 & 0xFFFFF) * EMB + kc * 8);
      ulonglong2 r2 = *(const ulonglong2*)(hsrc + (size_t)(p2 & 0xFFFFF) * EMB + kc * 8);
      ulonglong2 r3 = *(const ulonglong2*)(hsrc + (size_t)(p3 & 0xFFFFF) * EMB + kc * 8);
      ulonglong2 rr[4] = {r0, r1, r2, r3};
      int pp[4] = {p0, p1, p2, p3};
#pragma unroll
      for (int u = 0; u < 4; ++u) {
        half8 cc = *(const half8*)(cbh + (size_t)(pp[u] >> 20) * EMB + kc * 8);
        _Float16* sp = (_Float16*)&rr[u];
#pragma unroll
        for (int j = 0; j < 8; ++j) {
          float v = (float)sp[j];
          if (NORM) v = fmaxf(v * scv[j] + shv[j], 0.f);
          av[j] += fmaxf(v + (float)cc[j], 0.f);
        }
      }
    }
    for (; e < s1; ++e) {
      int p0 = csr[e];
      ulonglong2 r0 = *(const ulonglong2*)(hsrc + (size_t)(p0 & 0xFFFFF) * EMB + kc * 8);
      half8 cc = *(const half8*)(cbh + (size_t)(p0 >> 20) * EMB + kc * 8);
      _Float16* sp = (_Float16*)&r0;
#pragma unroll
      for (int j = 0; j < 8; ++j) {
        float v = (float)sp[j];
        if (NORM) v = fmaxf(v * scv[j] + shv[j], 0.f);
        av[j] += fmaxf(v + (float)cc[j], 0.f);
      }
    }
  }
  _Float16 o[8];
#pragma unroll
  for (int j = 0; j < 8; ++j) o[j] = (_Float16)av[j];
  *(ulonglong2*)(Af + (size_t)node * EMB + kc * 8) = *(ulonglong2*)o;
}

// ---------------- mlp: EXACT R0 structure (16KB Ws, 4-barrier LDS pipeline) ----------
// R8 proved this staging IS the software pipeline: direct-L2 W reads exposed ~200cy
// latency per MFMA (56 -> 124 us). Do not remove.
__global__ __launch_bounds__(256, 4) void mlp_kernel(
    const _Float16* __restrict__ Af, const _Float16* __restrict__ W1f,
    const _Float16* __restrict__ W2f,
    const float* __restrict__ b1g, const float* __restrict__ b2g,
    _Float16* __restrict__ hpre, float* __restrict__ slots) {
  __shared__ __align__(16) _Float16 Ws[16 * 64 * 8];  // 16KB, W1 then W2 per chunk

  const int t = threadIdx.x;
  const int w = t >> 6;
  const int lane = t & 63;
  const int q = lane >> 4, l15 = lane & 15;
  const int gw = blockIdx.x * 4 + w;   // global wave id, 0..6255
  const int n0 = gw * 16;              // 16 nodes per wave
  float* sums = slots + (size_t)(gw & 31) * 256;

  // ---- A fragments loaded ONCE, held across all chunks ----
  half8 nh[4];
#pragma unroll
  for (int kt = 0; kt < 4; ++kt)
    nh[kt] = *(const half8*)(Af + (size_t)(n0 + l15) * EMB + kt * 32 + q * 8);

  f32x4 oacc[8];  // [out col tile]
#pragma unroll
  for (int a = 0; a < 8; ++a) oacc[a] = (f32x4){0.f, 0.f, 0.f, 0.f};

  const int srcA = ((q & 1) * 2) * 16 + l15;  // quad permutation sources
  const int srcB = srcA + 16;
  const bool sel = (q >> 1) != 0;

  for (int c = 0; c < 4; ++c) {
    __syncthreads();  // prev chunk's stage-2 LDS reads complete
    // ---- stage W1 chunk c (wave w covers frags w*4..w*4+3) ----
    {
      const _Float16* gb = W1f + ((size_t)(c * 16 + w * 4) * 64 + lane) * 8;
#pragma unroll
      for (int j = 0; j < 4; ++j)
        *(ulonglong2*)&Ws[(w * 4 + j) * 512 + lane * 8] =
            *(const ulonglong2*)(gb + (size_t)j * 512);
    }
    __syncthreads();

    // ---- stage 1: hmidT[col c*64+colt*16+q*4+r][node l15] ----
    f32x4 hacc[4];
#pragma unroll
    for (int a = 0; a < 4; ++a) hacc[a] = (f32x4){0.f, 0.f, 0.f, 0.f};
#pragma unroll
    for (int kt = 0; kt < 4; ++kt) {
#pragma unroll
      for (int colt = 0; colt < 4; ++colt) {
        half8 wh = *(const half8*)&Ws[(kt * 4 + colt) * 512 + lane * 8];
        hacc[colt] = __builtin_amdgcn_mfma_f32_16x16x32_f16(wh, nh[kt], hacc[colt], 0, 0, 0);
      }
    }
    __syncthreads();  // stage-1 LDS reads complete; buffer reusable

    // ---- stage W2 chunk c ----
    {
      const _Float16* gb = W2f + ((size_t)(c * 16 + w * 4) * 64 + lane) * 8;
#pragma unroll
      for (int j = 0; j < 4; ++j)
        *(ulonglong2*)&Ws[(w * 4 + j) * 512 + lane * 8] =
            *(const ulonglong2*)(gb + (size_t)j * 512);
    }

    // ---- bias + relu + pack to f16 pairs (overlaps staging) ----
    u32 P01[4], P23[4];  // [colt]
#pragma unroll
    for (int colt = 0; colt < 4; ++colt) {
      float4 b1v = ld4(b1g + c * 64 + colt * 16 + q * 4);
      float v0 = fmaxf(hacc[colt][0] + b1v.x, 0.f);
      float v1 = fmaxf(hacc[colt][1] + b1v.y, 0.f);
      float v2 = fmaxf(hacc[colt][2] + b1v.z, 0.f);
      float v3 = fmaxf(hacc[colt][3] + b1v.w, 0.f);
      P01[colt] = packh2(v0, v1);
      P23[colt] = packh2(v2, v3);
    }
    __syncthreads();  // W2 staged

    // ---- stage 2: quad-permute hmid into B-frags, multiply with W2 from LDS ----
#pragma unroll
    for (int ktl = 0; ktl < 2; ++ktl) {
      half8 bh;
      {
        union { u32 d[4]; half8 s; } uh;
        int c0 = 2 * ktl, c1 = 2 * ktl + 1;
        u32 a0, a1;
        a0 = (u32)__shfl((int)P01[c0], srcA); a1 = (u32)__shfl((int)P01[c1], srcA);
        uh.d[0] = sel ? a1 : a0;
        a0 = (u32)__shfl((int)P23[c0], srcA); a1 = (u32)__shfl((int)P23[c1], srcA);
        uh.d[1] = sel ? a1 : a0;
        a0 = (u32)__shfl((int)P01[c0], srcB); a1 = (u32)__shfl((int)P01[c1], srcB);
        uh.d[2] = sel ? a1 : a0;
        a0 = (u32)__shfl((int)P23[c0], srcB); a1 = (u32)__shfl((int)P23[c1], srcB);
        uh.d[3] = sel ? a1 : a0;
        bh = uh.s;
      }
#pragma unroll
      for (int nt = 0; nt < 8; ++nt) {
        half8 wh = *(const half8*)&Ws[(ktl * 8 + nt) * 512 + lane * 8];
        oacc[nt] = __builtin_amdgcn_mfma_f32_16x16x32_f16(wh, bh, oacc[nt], 0, 0, 0);
      }
    }
  }

  // ---- epilogue: +b2, packed f16 store (8B), BN partials into slot ----
  const int node = n0 + l15;
#pragma unroll
  for (int nt = 0; nt < 8; ++nt) {
    int ocb = nt * 16 + q * 4;  // 4 consecutive out cols per lane
    float4 b2v = ld4(b2g + ocb);
    f32x4 s = (f32x4){0.f, 0.f, 0.f, 0.f};
    f32x4 s2 = (f32x4){0.f, 0.f, 0.f, 0.f};
    if (node < NN) {
      float v0 = oacc[nt][0] + b2v.x;
      float v1 = oacc[nt][1] + b2v.y;
      float v2 = oacc[nt][2] + b2v.z;
      float v3 = oacc[nt][3] + b2v.w;
      u64 pk = (u64)packh2(v0, v1) | ((u64)packh2(v2, v3) << 32);
      *(u64*)(hpre + (size_t)node * EMB + ocb) = pk;
      s[0] = v0; s[1] = v1; s[2] = v2; s[3] = v3;
      s2[0] = v0 * v0; s2[1] = v1 * v1; s2[2] = v2 * v2; s2[3] = v3 * v3;
    }
#pragma unroll
    for (int d = 1; d < 16; d <<= 1) {
#pragma unroll
      for (int r = 0; r < 4; ++r) {
        s[r] += __shfl_xor(s[r], d);
        s2[r] += __shfl_xor(s2[r], d);
      }
    }
    if (l15 == 0) {
#pragma unroll
      for (int r = 0; r < 4; ++r) {
        atomicAdd(&sums[ocb + r], s[r]);
        atomicAdd(&sums[128 + ocb + r], s2[r]);
      }
    }
  }
}

// ---------------- final output: out = hpre*sc + sh (f32, no relu); stats in-block ----
__global__ __launch_bounds__(256) void out_kernel(
    const _Float16* __restrict__ hpre, const float* __restrict__ slots,
    const float* __restrict__ gamma, const float* __restrict__ beta,
    float* __restrict__ out) {
  __shared__ float s_sc[128], s_sh[128];
  int t = threadIdx.x;
  if (t < 128) {
    float s = 0.f, s2 = 0.f;
#pragma unroll 8
    for (int k = 0; k < 32; ++k) {
      s += slots[k * 256 + t];
      s2 += slots[k * 256 + 128 + t];
    }
    float mean = s * (1.0f / NN);
    float var = s2 * (1.0f / NN) - mean * mean;  // biased
    float sc = gamma[t] * rsqrtf(var + 1e-5f);
    s_sc[t] = sc;
    s_sh[t] = beta[t] - mean * sc;
  }
  __syncthreads();
  int tid = blockIdx.x * blockDim.x + t;
  int n = tid >> 4;
  if (n >= NN) return;
  int kc = tid & 15;
  ulonglong2 raw = *(const ulonglong2*)(hpre + (size_t)n * EMB + kc * 8);
  _Float16* hr = (_Float16*)&raw;
  float v[8];
#pragma unroll
  for (int j = 0; j < 8; ++j) v[j] = (float)hr[j] * s_sc[kc * 8 + j] + s_sh[kc * 8 + j];
  float* d = out + (size_t)n * EMB + kc * 8;
  *(float4*)d = make_float4(v[0], v[1], v[2], v[3]);
  *(float4*)(d + 4) = make_float4(v[4], v[5], v[6], v[7]);
}

// ---------------- launch ----------------
extern "C" void kernel_launch(void* const* d_in, const int* in_sizes, int n_in,
                              void* d_out, int out_size, void* d_ws, size_t ws_size,
                              hipStream_t stream) {
  const int* x = (const int*)d_in[0];
  const int* ei = (const int*)d_in[1];
  const int* ea = (const int*)d_in[2];
  const float* x_emb1 = (const float*)d_in[3];
  const float* x_emb2 = (const float*)d_in[4];
  const float* ee1 = (const float*)d_in[5];
  const float* ee2 = (const float*)d_in[6];
  const float* W1 = (const float*)d_in[7];
  const float* b1 = (const float*)d_in[8];
  const float* W2 = (const float*)d_in[9];
  const float* b2 = (const float*)d_in[10];
  const float* eps = (const float*)d_in[11];
  const float* gamma = (const float*)d_in[12];
  const float* beta = (const float*)d_in[13];
  float* out = (float*)d_out;

  // workspace layout (16B-aligned sections)
  float* slots = (float*)d_ws;                  // 5*32*256 BN partial slots
  _Float16* hpre = (_Float16*)(slots + 5 * 32 * 256);  // NN*128 f16
  _Float16* Af = hpre + (size_t)NN * EMB;       // NPAD*128 f16
  _Float16* hb = Af + (size_t)NPAD * EMB;       // NN*128 f16
  _Float16* W1f = hb + (size_t)NN * EMB;        // 5*32768 f16
  _Float16* W2f = W1f + 5 * 32768;              // 5*32768 f16
  _Float16* cbh = W2f + 5 * 32768;              // 5*15*128 f16 combos
  int* deg = (int*)(cbh + 5 * 15 * 128 + 64);   // NN (pad to 16B boundary)
  int* off = deg + NN;                          // NN+1
  int* csr = off + NN + 1;                      // NE
  int* bsum = csr + NE;                         // 128
  int* gbins = bsum + 128;                      // 64 degree-bin starts
  int* perm = gbins + 64;                       // NN degree-sorted node order

  const int NB_SCAN = (NN + 1023) / 1024;

  // one-time per launch: CSR + degree-sort + combo tables + frag-ordered f16 weights
  hipMemsetAsync(deg, 0, NN * sizeof(int), stream);
  hipMemsetAsync(gbins, 0, 64 * sizeof(int), stream);
  hipMemsetAsync(slots, 0, 5 * 32 * 256 * sizeof(float), stream);
  hist_kernel<<<(NE + 255) / 256, 256, 0, stream>>>(ei, deg);
  scan1_kernel<<<NB_SCAN, 256, 0, stream>>>(deg, off, bsum, gbins);
  scan2_kernel<<<1, 128, 0, stream>>>(bsum, off, NB_SCAN, gbins);
  scan3_kernel<<<(NN + 255) / 256, 256, 0, stream>>>(off, bsum, deg, gbins, perm);
  hipMemsetAsync(deg, 0, NN * sizeof(int), stream);
  scatter_kernel<<<(NE + 255) / 256, 256, 0, stream>>>(ei, ea, off, deg, csr);
  prep_kernel<<<(40960 + 9600 + 255) / 256, 256, 0, stream>>>(W1, W2, ee1, ee2, W1f,
                                                              W2f, cbh);
  node_init_kernel<<<NN * 16 / 256 + 1, 256, 0, stream>>>(x, x_emb1, x_emb2, hb);

  const int NBLK = NPAD / 64;  // 1564 blocks x 4 waves (16 nodes each)
  for (int i = 0; i < 5; ++i) {
    if (i == 0)
      agg_kernel<false><<<NPAD * 16 / 256, 256, 0, stream>>>(
          hb, nullptr, nullptr, nullptr, off, csr, cbh + (size_t)i * 15 * EMB,
          eps + i, perm, Af);
    else
      agg_kernel<true><<<NPAD * 16 / 256, 256, 0, stream>>>(
          hpre, slots + (size_t)(i - 1) * 32 * 256, gamma + (size_t)(i - 1) * EMB,
          beta + (size_t)(i - 1) * EMB, off, csr, cbh + (size_t)i * 15 * EMB,
          eps + i, perm, Af);
    mlp_kernel<<<NBLK, 256, 0, stream>>>(
        Af, W1f + (size_t)i * 32768, W2f + (size_t)i * 32768,
        b1 + (size_t)i * 256, b2 + (size_t)i * 128, hpre,
        slots + (size_t)i * 32 * 256);
  }
  out_kernel<<<NN * 16 / 256 + 1, 256, 0, stream>>>(
      hpre, slots + 4 * 32 * 256, gamma + 4 * EMB, beta + 4 * EMB, out);
}

// Round 10
// 601.430 us; speedup vs baseline: 1.3193x; 1.0827x over previous
//
#include <hip/hip_runtime.h>

#define NN 100000
#define NPAD 100096   // 6256 * 16, padded row count for guard-free GEMM
#define NE 600000
#define EMB 128

typedef unsigned short u16;
typedef unsigned int u32;
typedef unsigned long long u64;
typedef _Float16 half8 __attribute__((ext_vector_type(8)));
typedef float f32x4 __attribute__((ext_vector_type(4)));

__device__ __forceinline__ float4 ld4(const float* p) { return *(const float4*)p; }
__device__ __forceinline__ u32 packh2(float a, float b) {  // two f32 -> packed f16 pair
  union { _Float16 h[2]; u32 d; } u;
  u.h[0] = (_Float16)a;
  u.h[1] = (_Float16)b;
  return u.d;
}

// ---------------- node embedding init: hb(f16) = emb1[x0] + emb2[x1] ----------------
__global__ __launch_bounds__(256) void node_init_kernel(
    const int* __restrict__ x, const float* __restrict__ emb1,
    const float* __restrict__ emb2, _Float16* __restrict__ hb) {
  int tid = blockIdx.x * blockDim.x + threadIdx.x;
  int n = tid >> 4;
  if (n >= NN) return;
  int kc = tid & 15;
  int x0 = min(max(x[2 * n], 0), 118);
  int x1 = min(max(x[2 * n + 1], 0), 2);  // clip to NUM_CHIR-1
  const float* p1 = emb1 + (size_t)x0 * EMB + kc * 8;
  const float* p2 = emb2 + (size_t)x1 * EMB + kc * 8;
  _Float16 o[8];
#pragma unroll
  for (int j = 0; j < 8; ++j) o[j] = (_Float16)(p1[j] + p2[j]);
  *(ulonglong2*)(hb + (size_t)n * EMB + kc * 8) = *(ulonglong2*)o;
}

// ---------------- CSR build ----------------
__global__ __launch_bounds__(256) void hist_kernel(const int* __restrict__ ei,
                                                   int* __restrict__ deg) {
  int e = blockIdx.x * blockDim.x + threadIdx.x;
  if (e >= NE) return;
  atomicAdd(&deg[ei[NE + e]], 1);
}

// scan1 + degree-histogram (fused dhist)
__global__ __launch_bounds__(256) void scan1_kernel(const int* __restrict__ deg,
                                                    int* __restrict__ off,
                                                    int* __restrict__ bsum,
                                                    int* __restrict__ gbins) {
  __shared__ int s[256];
  __shared__ int l[33];
  int t = threadIdx.x;
  if (t < 33) l[t] = 0;
  int base = blockIdx.x * 1024 + t * 4;
  int v[4];
#pragma unroll
  for (int j = 0; j < 4; ++j) {
    int idx = base + j;
    v[j] = (idx < NN) ? deg[idx] : 0;
  }
  int tsum = v[0] + v[1] + v[2] + v[3];
  s[t] = tsum;
  __syncthreads();
  for (int d = 1; d < 256; d <<= 1) {
    int add = (t >= d) ? s[t - d] : 0;
    __syncthreads();
    s[t] += add;
    __syncthreads();
  }
  int run = s[t] - tsum;
#pragma unroll
  for (int j = 0; j < 4; ++j) {
    int idx = base + j;
    if (idx < NN) {
      off[idx] = run;
      atomicAdd(&l[32 - min(v[j], 32)], 1);
    }
    run += v[j];
  }
  if (t == 255) bsum[blockIdx.x] = s[255];
  __syncthreads();
  if (t < 33 && l[t]) atomicAdd(&gbins[t], l[t]);
}

// wave0: prefix-scan of block sums; wave1: prefix-scan of degree bins (fused dscan)
__global__ void scan2_kernel(int* __restrict__ bsum, int* __restrict__ off, int nb,
                             int* __restrict__ gbins) {
  int t = threadIdx.x;  // 128 threads
  if (t < 64) {
    int lane = t;
    int v0 = (lane < nb) ? bsum[lane] : 0;
    int v1 = (lane + 64 < nb) ? bsum[lane + 64] : 0;
    int s0 = v0, s1 = v1;
    for (int d = 1; d < 64; d <<= 1) {
      int t0 = __shfl_up(s0, d);
      int t1 = __shfl_up(s1, d);
      if (lane >= d) { s0 += t0; s1 += t1; }
    }
    int tot0 = __shfl(s0, 63);
    int tot1 = __shfl(s1, 63);
    if (lane < nb) bsum[lane] = s0 - v0;                 // exclusive prefix
    if (lane + 64 < nb) bsum[lane + 64] = tot0 + s1 - v1;
    if (lane == 0) off[NN] = tot0 + tot1;
  } else {
    int lane = t - 64;
    int v = (lane < 33) ? gbins[lane] : 0;
    int s = v;
    for (int d = 1; d < 64; d <<= 1) {
      int tt = __shfl_up(s, d);
      if (lane >= d) s += tt;
    }
    if (lane < 33) gbins[lane] = s - v;  // exclusive bin starts
  }
}

// scan3 + degree-bucket scatter (fused dscatter): perm = nodes in DESCENDING degree
__global__ __launch_bounds__(256) void scan3_kernel(int* __restrict__ off,
                                                    const int* __restrict__ bsum,
                                                    const int* __restrict__ deg,
                                                    int* __restrict__ gbins,
                                                    int* __restrict__ perm) {
  __shared__ int lcnt[33], lbase[33];
  int t = threadIdx.x;
  if (t < 33) lcnt[t] = 0;
  __syncthreads();
  int idx = blockIdx.x * 256 + t;
  int b = 0, r = 0;
  if (idx < NN) {
    off[idx] += bsum[idx >> 10];
    b = 32 - min(deg[idx], 32);
    r = atomicAdd(&lcnt[b], 1);
  }
  __syncthreads();
  if (t < 33) lbase[t] = lcnt[t] ? atomicAdd(&gbins[t], lcnt[t]) : 0;
  __syncthreads();
  if (idx < NN) perm[lbase[b] + r] = idx;
}

__global__ __launch_bounds__(256) void scatter_kernel(
    const int* __restrict__ ei, const int* __restrict__ ea,
    const int* __restrict__ off, int* __restrict__ cnt, int* __restrict__ csr) {
  int e = blockIdx.x * blockDim.x + threadIdx.x;
  if (e >= NE) return;
  int d = ei[NE + e];
  int s = ei[e];
  int a0 = min(max(ea[2 * e], 0), 4);
  int a1 = min(max(ea[2 * e + 1], 0), 2);
  int code = a0 * 3 + a1;  // [0,14]
  int r = atomicAdd(&cnt[d], 1);
  csr[off[d] + r] = s | (code << 20);
}

// ---------------- merged weight/combo prep: frag-ordered f16 W1/W2 + f16 combos ------
__global__ __launch_bounds__(256) void prep_kernel(
    const float* __restrict__ W1g, const float* __restrict__ W2g,
    const float* __restrict__ ee1, const float* __restrict__ ee2,
    _Float16* __restrict__ W1f, _Float16* __restrict__ W2f,
    _Float16* __restrict__ cbh) {
  int idx = blockIdx.x * blockDim.x + threadIdx.x;
  _Float16 o[8];
  if (idx < 20480) {
    int lane = idx & 63;
    int r = idx >> 6;             // l*64 + c*16 + kt*4 + colt
    int nt = r & 3, kt = (r >> 2) & 3, c = (r >> 4) & 3, l = r >> 6;
    int n = c * 64 + nt * 16 + (lane & 15);
    int kb = kt * 32 + (lane >> 4) * 8;
#pragma unroll
    for (int j = 0; j < 8; ++j) o[j] = (_Float16)W1g[((size_t)l * 128 + kb + j) * 256 + n];
    *(ulonglong2*)(W1f + (size_t)idx * 8) = *(ulonglong2*)o;
  } else if (idx < 40960) {
    int i2 = idx - 20480;
    int lane = i2 & 63;
    int r = i2 >> 6;              // l*64 + c*16 + ktl*8 + nt
    int nt = r & 7, ktl = (r >> 3) & 1, c = (r >> 4) & 3, l = r >> 6;
    int n = nt * 16 + (lane & 15);
    int kb = c * 64 + ktl * 32 + (lane >> 4) * 8;
#pragma unroll
    for (int j = 0; j < 8; ++j) o[j] = (_Float16)W2g[((size_t)l * 256 + kb + j) * 128 + n];
    *(ulonglong2*)(W2f + (size_t)i2 * 8) = *(ulonglong2*)o;
  } else if (idx < 40960 + 9600) {
    int i3 = idx - 40960;
    int l = i3 / (15 * 128);
    int rem = i3 % (15 * 128);
    int code = rem / 128;
    int f = rem % 128;
    cbh[i3] = (_Float16)(ee1[(l * 5 + code / 3) * 128 + f] + ee2[(l * 3 + code % 3) * 128 + f]);
  }
}

// ---------------- FUSED layer: gather(agg-exact) -> staged A -> R0 mlp pipeline -------
// One dispatch per layer. 1564 blocks x 4 waves x 16 nodes. Gather keeps agg's
// 16-lane-per-node coalesced pattern (4 passes x 4 nodes per wave; degree-sorted perm
// makes the 4 concurrent edge loops uniform). A-tiles staged through the wave-private
// 4KB slice of Ws (dead before W1 staging reuses it). GEMM loop verbatim R0 (proven).
// hp0/hp1 ping-pong removes the Af round-trip entirely.
template <bool NORM>
__global__ __launch_bounds__(256, 4) void fused_kernel(
    const _Float16* __restrict__ hsrc, const float* __restrict__ slots_prev,
    const float* __restrict__ gamma, const float* __restrict__ beta,
    const int* __restrict__ off, const int* __restrict__ csr,
    const _Float16* __restrict__ cbh, const float* __restrict__ epsp,
    const int* __restrict__ perm,
    const _Float16* __restrict__ W1f, const _Float16* __restrict__ W2f,
    const float* __restrict__ b1g, const float* __restrict__ b2g,
    _Float16* __restrict__ hout, float* __restrict__ slots_out) {
  __shared__ __align__(16) _Float16 Ws[16 * 64 * 8];  // 16KB: gather staging, then W
  __shared__ float s_sc[128], s_sh[128];

  const int t = threadIdx.x;
  const int w = t >> 6;
  const int lane = t & 63;
  const int q = lane >> 4, l15 = lane & 15;
  const int gw = blockIdx.x * 4 + w;   // global wave id, 0..6255
  const int n0 = gw * 16;              // 16 perm-slots per wave
  float* sums = slots_out + (size_t)(gw & 31) * 256;

  // ---- BN stats of previous layer (in-block, bitwise-identical reduction) ----
  if (NORM) {
    if (t < 128) {
      float s = 0.f, s2 = 0.f;
#pragma unroll 8
      for (int k = 0; k < 32; ++k) {
        s += slots_prev[k * 256 + t];
        s2 += slots_prev[k * 256 + 128 + t];
      }
      float mean = s * (1.0f / NN);
      float var = s2 * (1.0f / NN) - mean * mean;  // biased
      float sc = gamma[t] * rsqrtf(var + 1e-5f);
      s_sc[t] = sc;
      s_sh[t] = beta[t] - mean * sc;
    }
    __syncthreads();
  }

  // ---- gather phase: 4 passes x 4 nodes, agg-exact 16-lane-per-node ----
  {
    const int sub = q;   // node-within-group
    const int kc = l15;  // feature slice
    float scv[8], shv[8];
    if (NORM) {
#pragma unroll
      for (int j = 0; j < 8; ++j) {
        scv[j] = s_sc[kc * 8 + j];
        shv[j] = s_sh[kc * 8 + j];
      }
    }
    const float eps1 = 1.0f + *epsp;
    half8 c0 = *(const half8*)(cbh + kc * 8);  // self-loop combo (code 0)
    for (int p = 0; p < 4; ++p) {
      int g = n0 + p * 4 + sub;
      float av[8] = {0.f, 0.f, 0.f, 0.f, 0.f, 0.f, 0.f, 0.f};
      if (g < NN) {
        int node = perm[g];
        ulonglong2 hraw = *(const ulonglong2*)(hsrc + (size_t)node * EMB + kc * 8);
        _Float16* hr = (_Float16*)&hraw;
#pragma unroll
        for (int j = 0; j < 8; ++j) {
          float hv = (float)hr[j];
          if (NORM) hv = fmaxf(hv * scv[j] + shv[j], 0.f);
          av[j] = eps1 * hv + fmaxf(hv + (float)c0[j], 0.f);
        }
        int s0 = off[node], s1 = off[node + 1];
        int e = s0;
        for (; e + 3 < s1; e += 4) {  // unroll x4: four gather chains in flight
          int p0 = csr[e], p1 = csr[e + 1], p2 = csr[e + 2], p3 = csr[e + 3];
          ulonglong2 r0 = *(const ulonglong2*)(hsrc + (size_t)(p0 & 0xFFFFF) * EMB + kc * 8);
          ulonglong2 r1 = *(const ulonglong2*)(hsrc + (size_t)(p1 & 0xFFFFF) * EMB + kc * 8);
          ulonglong2 r2 = *(const ulonglong2*)(hsrc + (size_t)(p2 & 0xFFFFF) * EMB + kc * 8);
          ulonglong2 r3 = *(const ulonglong2*)(hsrc + (size_t)(p3 & 0xFFFFF) * EMB + kc * 8);
          ulonglong2 rr[4] = {r0, r1, r2, r3};
          int pp[4] = {p0, p1, p2, p3};
#pragma unroll
          for (int u = 0; u < 4; ++u) {
            half8 cc = *(const half8*)(cbh + (size_t)(pp[u] >> 20) * EMB + kc * 8);
            _Float16* sp = (_Float16*)&rr[u];
#pragma unroll
            for (int j = 0; j < 8; ++j) {
              float v = (float)sp[j];
              if (NORM) v = fmaxf(v * scv[j] + shv[j], 0.f);
              av[j] += fmaxf(v + (float)cc[j], 0.f);
            }
          }
        }
        for (; e < s1; ++e) {
          int p0 = csr[e];
          ulonglong2 r0 = *(const ulonglong2*)(hsrc + (size_t)(p0 & 0xFFFFF) * EMB + kc * 8);
          half8 cc = *(const half8*)(cbh + (size_t)(p0 >> 20) * EMB + kc * 8);
          _Float16* sp = (_Float16*)&r0;
#pragma unroll
          for (int j = 0; j < 8; ++j) {
            float v = (float)sp[j];
            if (NORM) v = fmaxf(v * scv[j] + shv[j], 0.f);
            av[j] += fmaxf(v + (float)cc[j], 0.f);
          }
        }
      }
      _Float16 o[8];
#pragma unroll
      for (int j = 0; j < 8; ++j) o[j] = (_Float16)av[j];
      // wave-private staging slice: row (p*4+sub) of this wave's 16x128 A-tile
      *(ulonglong2*)&Ws[w * 2048 + (p * 4 + sub) * 128 + kc * 8] = *(ulonglong2*)o;
    }
  }

  // ---- A fragments from own staging slice (same-wave LDS dependency: no barrier) ----
  half8 nh[4];
#pragma unroll
  for (int kt = 0; kt < 4; ++kt)
    nh[kt] = *(const half8*)&Ws[w * 2048 + l15 * 128 + kt * 32 + q * 8];

  f32x4 oacc[8];  // [out col tile]
#pragma unroll
  for (int a = 0; a < 8; ++a) oacc[a] = (f32x4){0.f, 0.f, 0.f, 0.f};

  const int srcA = ((q & 1) * 2) * 16 + l15;  // quad permutation sources
  const int srcB = srcA + 16;
  const bool sel = (q >> 1) != 0;

  for (int c = 0; c < 4; ++c) {
    __syncthreads();  // prev chunk's stage-2 LDS reads complete (c=0: gather reads done)
    // ---- stage W1 chunk c (wave w covers frags w*4..w*4+3 = its own 4KB slice) ----
    {
      const _Float16* gb = W1f + ((size_t)(c * 16 + w * 4) * 64 + lane) * 8;
#pragma unroll
      for (int j = 0; j < 4; ++j)
        *(ulonglong2*)&Ws[(w * 4 + j) * 512 + lane * 8] =
            *(const ulonglong2*)(gb + (size_t)j * 512);
    }
    __syncthreads();

    // ---- stage 1: hmidT[col c*64+colt*16+q*4+r][node l15] ----
    f32x4 hacc[4];
#pragma unroll
    for (int a = 0; a < 4; ++a) hacc[a] = (f32x4){0.f, 0.f, 0.f, 0.f};
#pragma unroll
    for (int kt = 0; kt < 4; ++kt) {
#pragma unroll
      for (int colt = 0; colt < 4; ++colt) {
        half8 wh = *(const half8*)&Ws[(kt * 4 + colt) * 512 + lane * 8];
        hacc[colt] = __builtin_amdgcn_mfma_f32_16x16x32_f16(wh, nh[kt], hacc[colt], 0, 0, 0);
      }
    }
    __syncthreads();  // stage-1 LDS reads complete; buffer reusable

    // ---- stage W2 chunk c ----
    {
      const _Float16* gb = W2f + ((size_t)(c * 16 + w * 4) * 64 + lane) * 8;
#pragma unroll
      for (int j = 0; j < 4; ++j)
        *(ulonglong2*)&Ws[(w * 4 + j) * 512 + lane * 8] =
            *(const ulonglong2*)(gb + (size_t)j * 512);
    }

    // ---- bias + relu + pack to f16 pairs (overlaps staging) ----
    u32 P01[4], P23[4];  // [colt]
#pragma unroll
    for (int colt = 0; colt < 4; ++colt) {
      float4 b1v = ld4(b1g + c * 64 + colt * 16 + q * 4);
      float v0 = fmaxf(hacc[colt][0] + b1v.x, 0.f);
      float v1 = fmaxf(hacc[colt][1] + b1v.y, 0.f);
      float v2 = fmaxf(hacc[colt][2] + b1v.z, 0.f);
      float v3 = fmaxf(hacc[colt][3] + b1v.w, 0.f);
      P01[colt] = packh2(v0, v1);
      P23[colt] = packh2(v2, v3);
    }
    __syncthreads();  // W2 staged

    // ---- stage 2: quad-permute hmid into B-frags, multiply with W2 from LDS ----
#pragma unroll
    for (int ktl = 0; ktl < 2; ++ktl) {
      half8 bh;
      {
        union { u32 d[4]; half8 s; } uh;
        int c0 = 2 * ktl, c1 = 2 * ktl + 1;
        u32 a0, a1;
        a0 = (u32)__shfl((int)P01[c0], srcA); a1 = (u32)__shfl((int)P01[c1], srcA);
        uh.d[0] = sel ? a1 : a0;
        a0 = (u32)__shfl((int)P23[c0], srcA); a1 = (u32)__shfl((int)P23[c1], srcA);
        uh.d[1] = sel ? a1 : a0;
        a0 = (u32)__shfl((int)P01[c0], srcB); a1 = (u32)__shfl((int)P01[c1], srcB);
        uh.d[2] = sel ? a1 : a0;
        a0 = (u32)__shfl((int)P23[c0], srcB); a1 = (u32)__shfl((int)P23[c1], srcB);
        uh.d[3] = sel ? a1 : a0;
        bh = uh.s;
      }
#pragma unroll
      for (int nt = 0; nt < 8; ++nt) {
        half8 wh = *(const half8*)&Ws[(ktl * 8 + nt) * 512 + lane * 8];
        oacc[nt] = __builtin_amdgcn_mfma_f32_16x16x32_f16(wh, bh, oacc[nt], 0, 0, 0);
      }
    }
  }

  // ---- epilogue: +b2, packed f16 store (8B), BN partials into slot ----
  const int gg = n0 + l15;
  const bool ok = gg < NN;
  const int node = ok ? perm[gg] : 0;
#pragma unroll
  for (int nt = 0; nt < 8; ++nt) {
    int ocb = nt * 16 + q * 4;  // 4 consecutive out cols per lane
    float4 b2v = ld4(b2g + ocb);
    f32x4 s = (f32x4){0.f, 0.f, 0.f, 0.f};
    f32x4 s2 = (f32x4){0.f, 0.f, 0.f, 0.f};
    if (ok) {
      float v0 = oacc[nt][0] + b2v.x;
      float v1 = oacc[nt][1] + b2v.y;
      float v2 = oacc[nt][2] + b2v.z;
      float v3 = oacc[nt][3] + b2v.w;
      u64 pk = (u64)packh2(v0, v1) | ((u64)packh2(v2, v3) << 32);
      *(u64*)(hout + (size_t)node * EMB + ocb) = pk;
      s[0] = v0; s[1] = v1; s[2] = v2; s[3] = v3;
      s2[0] = v0 * v0; s2[1] = v1 * v1; s2[2] = v2 * v2; s2[3] = v3 * v3;
    }
#pragma unroll
    for (int d = 1; d < 16; d <<= 1) {
#pragma unroll
      for (int r = 0; r < 4; ++r) {
        s[r] += __shfl_xor(s[r], d);
        s2[r] += __shfl_xor(s2[r], d);
      }
    }
    if (l15 == 0) {
#pragma unroll
      for (int r = 0; r < 4; ++r) {
        atomicAdd(&sums[ocb + r], s[r]);
        atomicAdd(&sums[128 + ocb + r], s2[r]);
      }
    }
  }
}

// ---------------- final output: out = h*sc + sh (f32, no relu); stats in-block ----
__global__ __launch_bounds__(256) void out_kernel(
    const _Float16* __restrict__ hpre, const float* __restrict__ slots,
    const float* __restrict__ gamma, const float* __restrict__ beta,
    float* __restrict__ out) {
  __shared__ float s_sc[128], s_sh[128];
  int t = threadIdx.x;
  if (t < 128) {
    float s = 0.f, s2 = 0.f;
#pragma unroll 8
    for (int k = 0; k < 32; ++k) {
      s += slots[k * 256 + t];
      s2 += slots[k * 256 + 128 + t];
    }
    float mean = s * (1.0f / NN);
    float var = s2 * (1.0f / NN) - mean * mean;  // biased
    float sc = gamma[t] * rsqrtf(var + 1e-5f);
    s_sc[t] = sc;
    s_sh[t] = beta[t] - mean * sc;
  }
  __syncthreads();
  int tid = blockIdx.x * blockDim.x + t;
  int n = tid >> 4;
  if (n >= NN) return;
  int kc = tid & 15;
  ulonglong2 raw = *(const ulonglong2*)(hpre + (size_t)n * EMB + kc * 8);
  _Float16* hr = (_Float16*)&raw;
  float v[8];
#pragma unroll
  for (int j = 0; j < 8; ++j) v[j] = (float)hr[j] * s_sc[kc * 8 + j] + s_sh[kc * 8 + j];
  float* d = out + (size_t)n * EMB + kc * 8;
  *(float4*)d = make_float4(v[0], v[1], v[2], v[3]);
  *(float4*)(d + 4) = make_float4(v[4], v[5], v[6], v[7]);
}

// ---------------- launch ----------------
extern "C" void kernel_launch(void* const* d_in, const int* in_sizes, int n_in,
                              void* d_out, int out_size, void* d_ws, size_t ws_size,
                              hipStream_t stream) {
  const int* x = (const int*)d_in[0];
  const int* ei = (const int*)d_in[1];
  const int* ea = (const int*)d_in[2];
  const float* x_emb1 = (const float*)d_in[3];
  const float* x_emb2 = (const float*)d_in[4];
  const float* ee1 = (const float*)d_in[5];
  const float* ee2 = (const float*)d_in[6];
  const float* W1 = (const float*)d_in[7];
  const float* b1 = (const float*)d_in[8];
  const float* W2 = (const float*)d_in[9];
  const float* b2 = (const float*)d_in[10];
  const float* eps = (const float*)d_in[11];
  const float* gamma = (const float*)d_in[12];
  const float* beta = (const float*)d_in[13];
  float* out = (float*)d_out;

  // workspace layout (16B-aligned sections)
  float* slots = (float*)d_ws;                  // 5*32*256 BN partial slots
  _Float16* hp0 = (_Float16*)(slots + 5 * 32 * 256);  // NN*128 f16 (even layer out)
  _Float16* hp1 = hp0 + (size_t)NN * EMB;       // NN*128 f16 (odd layer out)
  _Float16* hb = hp1 + (size_t)NN * EMB;        // NN*128 f16 node embeddings
  _Float16* W1f = hb + (size_t)NN * EMB;        // 5*32768 f16
  _Float16* W2f = W1f + 5 * 32768;              // 5*32768 f16
  _Float16* cbh = W2f + 5 * 32768;              // 5*15*128 f16 combos
  int* deg = (int*)(cbh + 5 * 15 * 128 + 64);   // NN (pad to 16B boundary)
  int* off = deg + NN;                          // NN+1
  int* csr = off + NN + 1;                      // NE
  int* bsum = csr + NE;                         // 128
  int* gbins = bsum + 128;                      // 64 degree-bin starts
  int* perm = gbins + 64;                       // NN degree-sorted node order

  const int NB_SCAN = (NN + 1023) / 1024;

  // one-time per launch: CSR + degree-sort + combo tables + frag-ordered f16 weights
  hipMemsetAsync(deg, 0, NN * sizeof(int), stream);
  hipMemsetAsync(gbins, 0, 64 * sizeof(int), stream);
  hipMemsetAsync(slots, 0, 5 * 32 * 256 * sizeof(float), stream);
  hist_kernel<<<(NE + 255) / 256, 256, 0, stream>>>(ei, deg);
  scan1_kernel<<<NB_SCAN, 256, 0, stream>>>(deg, off, bsum, gbins);
  scan2_kernel<<<1, 128, 0, stream>>>(bsum, off, NB_SCAN, gbins);
  scan3_kernel<<<(NN + 255) / 256, 256, 0, stream>>>(off, bsum, deg, gbins, perm);
  hipMemsetAsync(deg, 0, NN * sizeof(int), stream);
  scatter_kernel<<<(NE + 255) / 256, 256, 0, stream>>>(ei, ea, off, deg, csr);
  prep_kernel<<<(40960 + 9600 + 255) / 256, 256, 0, stream>>>(W1, W2, ee1, ee2, W1f,
                                                              W2f, cbh);
  node_init_kernel<<<NN * 16 / 256 + 1, 256, 0, stream>>>(x, x_emb1, x_emb2, hb);

  const int NBLK = NPAD / 64;  // 1564 blocks x 4 waves (16 nodes each)
  for (int i = 0; i < 5; ++i) {
    // ping-pong: layer i reads hin, writes hout (i=0 reads hb)
    const _Float16* hin = (i == 0) ? hb : ((i & 1) ? hp0 : hp1);
    _Float16* hout = (i & 1) ? hp1 : hp0;
    if (i == 0)
      fused_kernel<false><<<NBLK, 256, 0, stream>>>(
          hin, nullptr, nullptr, nullptr, off, csr, cbh, eps, perm,
          W1f, W2f, b1, b2, hout, slots);
    else
      fused_kernel<true><<<NBLK, 256, 0, stream>>>(
          hin, slots + (size_t)(i - 1) * 32 * 256, gamma + (size_t)(i - 1) * EMB,
          beta + (size_t)(i - 1) * EMB, off, csr, cbh + (size_t)i * 15 * EMB,
          eps + i, perm, W1f + (size_t)i * 32768, W2f + (size_t)i * 32768,
          b1 + (size_t)i * 256, b2 + (size_t)i * 128, hout,
          slots + (size_t)i * 32 * 256);
  }
  out_kernel<<<NN * 16 / 256 + 1, 256, 0, stream>>>(
      hp0, slots + 4 * 32 * 256, gamma + 4 * EMB, beta + 4 * EMB, out);
}